// Round 10
// baseline (232.390 us; speedup 1.0000x reference)
//
#include <hip/hip_runtime.h>

#define C 128

typedef __attribute__((ext_vector_type(8))) short short8;
typedef __attribute__((ext_vector_type(16))) float floatx16;

__device__ __forceinline__ unsigned short f2b(float f) {
    union { float f; unsigned u; } v; v.f = f;
    unsigned u = v.u + 0x7fffu + ((v.u >> 16) & 1u);  // RNE
    return (unsigned short)(u >> 16);
}
__device__ __forceinline__ float b2f(unsigned short h) {
    union { unsigned u; float f; } v; v.u = ((unsigned)h) << 16;
    return v.f;
}
__device__ __forceinline__ void acc_pair(unsigned u, float& lo, float& hi) {
    union { unsigned u; float f; } a, b;
    a.u = u << 16;
    b.u = u & 0xffff0000u;
    lo += a.f;
    hi += b.f;
}

// ------- fused: fp32->bf16 casts (x, Wn, Wr, Wh) + degree histogram (one dispatch) -------
__global__ void cast_count_kernel(const float* __restrict__ x, unsigned short* __restrict__ xb, int n4x,
                                  const float* __restrict__ Wn, unsigned short* __restrict__ Wnb,
                                  const float* __restrict__ Wr, unsigned short* __restrict__ Wrb, int n4w,
                                  const float* __restrict__ Wh, unsigned short* __restrict__ Whb, int n4h,
                                  const int* __restrict__ dst, int* __restrict__ deg, int E,
                                  int castBlocks) {
    if ((int)blockIdx.x < castBlocks) {
        int i = blockIdx.x * blockDim.x + threadIdx.x;
        const float* in;
        unsigned short* out;
        int idx;
        if (i < n4x) { in = x; out = xb; idx = i; }
        else if (i < n4x + n4w) { in = Wn; out = Wnb; idx = i - n4x; }
        else if (i < n4x + 2 * n4w) { in = Wr; out = Wrb; idx = i - n4x - n4w; }
        else if (i < n4x + 2 * n4w + n4h) { in = Wh; out = Whb; idx = i - n4x - 2 * n4w; }
        else return;
        float4 v = ((const float4*)in)[idx];
        ushort4 o;
        o.x = f2b(v.x); o.y = f2b(v.y); o.z = f2b(v.z); o.w = f2b(v.w);
        ((ushort4*)out)[idx] = o;
    } else {
        int e = (blockIdx.x - castBlocks) * blockDim.x + threadIdx.x;
        if (e < E) atomicAdd(&deg[dst[e]], 1);
    }
}

// ---------------- scan phase 1: per-256-chunk sums ----------------
__global__ void scan_partial_kernel(const int* __restrict__ deg, int* __restrict__ blocksum, int n) {
    __shared__ int sm[256];
    int t = threadIdx.x;
    int i = blockIdx.x * 256 + t;
    sm[t] = (i < n) ? deg[i] : 0;
    __syncthreads();
#pragma unroll
    for (int off = 128; off > 0; off >>= 1) {
        if (t < off) sm[t] += sm[t + off];
        __syncthreads();
    }
    if (t == 0) blocksum[blockIdx.x] = sm[0];
}

// ---------------- scan phase 2 (merged): per-block offset + chunk scan + scatter ----------------
__global__ void scan_scatter_kernel(const int* __restrict__ deg, const int* __restrict__ blocksum,
                                    int* __restrict__ row_start, int* __restrict__ cursor,
                                    int n, int E) {
    __shared__ int osm[256];
    __shared__ int sm[256];
    int t = threadIdx.x, bid = blockIdx.x;
    int s = 0;
    for (int i = t; i < bid; i += 256) s += blocksum[i];
    osm[t] = s;
    __syncthreads();
#pragma unroll
    for (int off = 128; off > 0; off >>= 1) {
        if (t < off) osm[t] += osm[t + off];
        __syncthreads();
    }
    int boff = osm[0];
    int i = bid * 256 + t;
    int d = (i < n) ? deg[i] : 0;
    sm[t] = d;
    __syncthreads();
    for (int off = 1; off < 256; off <<= 1) {
        int v = (t >= off) ? sm[t - off] : 0;
        __syncthreads();
        sm[t] += v;
        __syncthreads();
    }
    int excl = sm[t] - d + boff;
    if (i < n) {
        row_start[i] = excl;
        cursor[i] = excl;
    }
    if (i == n - 1) row_start[n] = E;
}

// ---------------- bucket edges by dst (counting sort) ----------------
__global__ void bucket_kernel(const int* __restrict__ src, const int* __restrict__ dst,
                              int* __restrict__ cursor, int* __restrict__ esrc, int E) {
    int e = blockIdx.x * blockDim.x + threadIdx.x;
    if (e < E) {
        int d = dst[e];
        int p = atomicAdd(&cursor[d], 1);
        esrc[p] = src[e];
    }
}

// ---------------- mean aggregation: QUARTER-wave per node, 8-deep row ILP ----------------
__global__ void aggregate_kernel(const unsigned short* __restrict__ xb, const int* __restrict__ row_start,
                                 const int* __restrict__ esrc,
                                 unsigned short* __restrict__ agg, int n) {
    int wid = (blockIdx.x * blockDim.x + threadIdx.x) >> 6;
    int lane = threadIdx.x & 63;
    int q = lane >> 4, l16 = lane & 15;
    int qb = lane & 48;
    int node = wid * 4 + q;
    if (node >= n) return;

    int beg = row_start[node];
    int end = row_start[node + 1];
    size_t choff = (size_t)l16 * 8;

    float a0 = 0.f, a1 = 0.f, a2 = 0.f, a3 = 0.f, a4 = 0.f, a5 = 0.f, a6 = 0.f, a7 = 0.f;

    for (int base = beg; base < end; base += 16) {
        int cnt = min(end - base, 16);
        int e_val = (base + l16 < end) ? esrc[base + l16] : 0;
        int j = 0;
        for (; j + 8 <= cnt; j += 8) {
            int s0 = __shfl(e_val, qb | j, 64);
            int s1 = __shfl(e_val, qb | (j + 1), 64);
            int s2 = __shfl(e_val, qb | (j + 2), 64);
            int s3 = __shfl(e_val, qb | (j + 3), 64);
            int s4 = __shfl(e_val, qb | (j + 4), 64);
            int s5 = __shfl(e_val, qb | (j + 5), 64);
            int s6 = __shfl(e_val, qb | (j + 6), 64);
            int s7 = __shfl(e_val, qb | (j + 7), 64);
            uint4 v0 = *(const uint4*)(xb + (size_t)s0 * C + choff);
            uint4 v1 = *(const uint4*)(xb + (size_t)s1 * C + choff);
            uint4 v2 = *(const uint4*)(xb + (size_t)s2 * C + choff);
            uint4 v3 = *(const uint4*)(xb + (size_t)s3 * C + choff);
            uint4 v4 = *(const uint4*)(xb + (size_t)s4 * C + choff);
            uint4 v5 = *(const uint4*)(xb + (size_t)s5 * C + choff);
            uint4 v6 = *(const uint4*)(xb + (size_t)s6 * C + choff);
            uint4 v7 = *(const uint4*)(xb + (size_t)s7 * C + choff);
            acc_pair(v0.x, a0, a1); acc_pair(v0.y, a2, a3); acc_pair(v0.z, a4, a5); acc_pair(v0.w, a6, a7);
            acc_pair(v1.x, a0, a1); acc_pair(v1.y, a2, a3); acc_pair(v1.z, a4, a5); acc_pair(v1.w, a6, a7);
            acc_pair(v2.x, a0, a1); acc_pair(v2.y, a2, a3); acc_pair(v2.z, a4, a5); acc_pair(v2.w, a6, a7);
            acc_pair(v3.x, a0, a1); acc_pair(v3.y, a2, a3); acc_pair(v3.z, a4, a5); acc_pair(v3.w, a6, a7);
            acc_pair(v4.x, a0, a1); acc_pair(v4.y, a2, a3); acc_pair(v4.z, a4, a5); acc_pair(v4.w, a6, a7);
            acc_pair(v5.x, a0, a1); acc_pair(v5.y, a2, a3); acc_pair(v5.z, a4, a5); acc_pair(v5.w, a6, a7);
            acc_pair(v6.x, a0, a1); acc_pair(v6.y, a2, a3); acc_pair(v6.z, a4, a5); acc_pair(v6.w, a6, a7);
            acc_pair(v7.x, a0, a1); acc_pair(v7.y, a2, a3); acc_pair(v7.z, a4, a5); acc_pair(v7.w, a6, a7);
        }
        for (; j + 4 <= cnt; j += 4) {
            int s0 = __shfl(e_val, qb | j, 64);
            int s1 = __shfl(e_val, qb | (j + 1), 64);
            int s2 = __shfl(e_val, qb | (j + 2), 64);
            int s3 = __shfl(e_val, qb | (j + 3), 64);
            uint4 v0 = *(const uint4*)(xb + (size_t)s0 * C + choff);
            uint4 v1 = *(const uint4*)(xb + (size_t)s1 * C + choff);
            uint4 v2 = *(const uint4*)(xb + (size_t)s2 * C + choff);
            uint4 v3 = *(const uint4*)(xb + (size_t)s3 * C + choff);
            acc_pair(v0.x, a0, a1); acc_pair(v0.y, a2, a3); acc_pair(v0.z, a4, a5); acc_pair(v0.w, a6, a7);
            acc_pair(v1.x, a0, a1); acc_pair(v1.y, a2, a3); acc_pair(v1.z, a4, a5); acc_pair(v1.w, a6, a7);
            acc_pair(v2.x, a0, a1); acc_pair(v2.y, a2, a3); acc_pair(v2.z, a4, a5); acc_pair(v2.w, a6, a7);
            acc_pair(v3.x, a0, a1); acc_pair(v3.y, a2, a3); acc_pair(v3.z, a4, a5); acc_pair(v3.w, a6, a7);
        }
        for (; j < cnt; ++j) {
            int s0 = __shfl(e_val, qb | j, 64);
            uint4 v0 = *(const uint4*)(xb + (size_t)s0 * C + choff);
            acc_pair(v0.x, a0, a1); acc_pair(v0.y, a2, a3); acc_pair(v0.z, a4, a5); acc_pair(v0.w, a6, a7);
        }
    }

    float sc = 1.0f / fmaxf((float)(end - beg), 1.0f);
    uint4 o;
    o.x = ((unsigned)f2b(a1 * sc) << 16) | (unsigned)f2b(a0 * sc);
    o.y = ((unsigned)f2b(a3 * sc) << 16) | (unsigned)f2b(a2 * sc);
    o.z = ((unsigned)f2b(a5 * sc) << 16) | (unsigned)f2b(a4 * sc);
    o.w = ((unsigned)f2b(a7 * sc) << 16) | (unsigned)f2b(a6 * sc);
    *(uint4*)(agg + (size_t)node * C + choff) = o;
}

// ---- MFMA GEMM, 64-row blocks (h = agg@Wn^T + x@Wr^T + b) + LN + ReLU (+fused head) ----
// R9 known-good structure + (a) register-prefetch of phase-1 staging (Xin/Wr) issued
// before phase-0 MFMA, (b) optional in-kernel quarter-wave gather (gather!=0) replacing
// the Aagg read — used for the tiny final layer so its aggregate dispatch disappears.
__launch_bounds__(256)
__global__ void gemm_mfma_ln_relu_kernel(const unsigned short* __restrict__ Aagg,
                                         const unsigned short* __restrict__ Xin,
                                         const int* __restrict__ row_start,
                                         const int* __restrict__ esrc, int gather,
                                         const unsigned short* __restrict__ Wn,
                                         const unsigned short* __restrict__ Wr,
                                         const float* __restrict__ bconv, const float* __restrict__ gamma,
                                         const float* __restrict__ beta, unsigned short* __restrict__ Xout,
                                         int n,
                                         const unsigned short* __restrict__ Whb,
                                         const float* __restrict__ bh, float* __restrict__ out) {
    __shared__ unsigned short Xs[64][136];
    __shared__ unsigned short Ws[128][136];
    __shared__ float Ls[64][2];
    __shared__ float Lss[64][2];

    int tid = threadIdx.x;
    int wave = tid >> 6, lane = tid & 63;
    int rh = wave & 1, ch = wave >> 1;
    int l31 = lane & 31, half = lane >> 5;
    int row0 = blockIdx.x * 64;

    // ---- phase 0 staging: A tile (agg rows, read or gathered) + Wn ----
    if (gather) {
        int q = lane >> 4, l16 = lane & 15;
        int qb = lane & 48;
        size_t choff = (size_t)l16 * 8;
#pragma unroll
        for (int rnd = 0; rnd < 4; ++rnd) {
            int rl = wave * 16 + rnd * 4 + q;
            int node = row0 + rl;
            if (node < n) {
                int beg = row_start[node];
                int end = row_start[node + 1];
                float a0 = 0.f, a1 = 0.f, a2 = 0.f, a3 = 0.f, a4 = 0.f, a5 = 0.f, a6 = 0.f, a7 = 0.f;
                for (int base = beg; base < end; base += 16) {
                    int cnt = min(end - base, 16);
                    int e_val = (base + l16 < end) ? esrc[base + l16] : 0;
                    int j = 0;
                    for (; j + 4 <= cnt; j += 4) {
                        int s0 = __shfl(e_val, qb | j, 64);
                        int s1 = __shfl(e_val, qb | (j + 1), 64);
                        int s2 = __shfl(e_val, qb | (j + 2), 64);
                        int s3 = __shfl(e_val, qb | (j + 3), 64);
                        uint4 v0 = *(const uint4*)(Xin + (size_t)s0 * C + choff);
                        uint4 v1 = *(const uint4*)(Xin + (size_t)s1 * C + choff);
                        uint4 v2 = *(const uint4*)(Xin + (size_t)s2 * C + choff);
                        uint4 v3 = *(const uint4*)(Xin + (size_t)s3 * C + choff);
                        acc_pair(v0.x, a0, a1); acc_pair(v0.y, a2, a3); acc_pair(v0.z, a4, a5); acc_pair(v0.w, a6, a7);
                        acc_pair(v1.x, a0, a1); acc_pair(v1.y, a2, a3); acc_pair(v1.z, a4, a5); acc_pair(v1.w, a6, a7);
                        acc_pair(v2.x, a0, a1); acc_pair(v2.y, a2, a3); acc_pair(v2.z, a4, a5); acc_pair(v2.w, a6, a7);
                        acc_pair(v3.x, a0, a1); acc_pair(v3.y, a2, a3); acc_pair(v3.z, a4, a5); acc_pair(v3.w, a6, a7);
                    }
                    for (; j < cnt; ++j) {
                        int s0 = __shfl(e_val, qb | j, 64);
                        uint4 v0 = *(const uint4*)(Xin + (size_t)s0 * C + choff);
                        acc_pair(v0.x, a0, a1); acc_pair(v0.y, a2, a3); acc_pair(v0.z, a4, a5); acc_pair(v0.w, a6, a7);
                    }
                }
                float sc = 1.0f / fmaxf((float)(end - beg), 1.0f);
                uint4 o;
                o.x = ((unsigned)f2b(a1 * sc) << 16) | (unsigned)f2b(a0 * sc);
                o.y = ((unsigned)f2b(a3 * sc) << 16) | (unsigned)f2b(a2 * sc);
                o.z = ((unsigned)f2b(a5 * sc) << 16) | (unsigned)f2b(a4 * sc);
                o.w = ((unsigned)f2b(a7 * sc) << 16) | (unsigned)f2b(a6 * sc);
                *(uint4*)&Xs[rl][l16 * 8] = o;
            } else {
                *(uint4*)&Xs[rl][l16 * 8] = make_uint4(0u, 0u, 0u, 0u);
            }
        }
    } else {
#pragma unroll
        for (int i = 0; i < 4; ++i) {
            int cidx = tid + 256 * i;
            int r = cidx >> 4, koff = (cidx & 15) * 8;
            uint4 v = make_uint4(0u, 0u, 0u, 0u);
            int rg = row0 + r;
            if (rg < n) v = *(const uint4*)(Aagg + (size_t)rg * C + koff);
            *(uint4*)&Xs[r][koff] = v;
        }
    }
#pragma unroll
    for (int i = 0; i < 8; ++i) {
        int cidx = tid + 256 * i;
        int r = cidx >> 4, koff = (cidx & 15) * 8;
        uint4 v = *(const uint4*)(Wn + (size_t)r * C + koff);
        *(uint4*)&Ws[r][koff] = v;
    }

    // ---- prefetch phase-1 staging (Xin rows + Wr) into registers; consumed after phase 0 ----
    uint4 xreg[4], wreg[8];
#pragma unroll
    for (int i = 0; i < 4; ++i) {
        int cidx = tid + 256 * i;
        int r = cidx >> 4, koff = (cidx & 15) * 8;
        int rg = row0 + r;
        xreg[i] = (rg < n) ? *(const uint4*)(Xin + (size_t)rg * C + koff) : make_uint4(0u, 0u, 0u, 0u);
    }
#pragma unroll
    for (int i = 0; i < 8; ++i) {
        int cidx = tid + 256 * i;
        int r = cidx >> 4, koff = (cidx & 15) * 8;
        wreg[i] = *(const uint4*)(Wr + (size_t)r * C + koff);
    }

    floatx16 acc0, acc1;
#pragma unroll
    for (int i = 0; i < 16; ++i) { acc0[i] = 0.f; acc1[i] = 0.f; }

    __syncthreads();
    // phase 0 MFMA: agg @ Wn^T
#pragma unroll
    for (int kc = 0; kc < C; kc += 16) {
        int ko = kc + half * 8;
        short8 a = *(const short8*)&Xs[rh * 32 + l31][ko];
        short8 b0 = *(const short8*)&Ws[ch * 64 + l31][ko];
        short8 b1 = *(const short8*)&Ws[ch * 64 + 32 + l31][ko];
        acc0 = __builtin_amdgcn_mfma_f32_32x32x16_bf16(a, b0, acc0, 0, 0, 0);
        acc1 = __builtin_amdgcn_mfma_f32_32x32x16_bf16(a, b1, acc1, 0, 0, 0);
    }
    __syncthreads();
    // phase 1 staging from prefetch registers
#pragma unroll
    for (int i = 0; i < 4; ++i) {
        int cidx = tid + 256 * i;
        int r = cidx >> 4, koff = (cidx & 15) * 8;
        *(uint4*)&Xs[r][koff] = xreg[i];
    }
#pragma unroll
    for (int i = 0; i < 8; ++i) {
        int cidx = tid + 256 * i;
        int r = cidx >> 4, koff = (cidx & 15) * 8;
        *(uint4*)&Ws[r][koff] = wreg[i];
    }
    __syncthreads();
    // phase 1 MFMA: x @ Wr^T
#pragma unroll
    for (int kc = 0; kc < C; kc += 16) {
        int ko = kc + half * 8;
        short8 a = *(const short8*)&Xs[rh * 32 + l31][ko];
        short8 b0 = *(const short8*)&Ws[ch * 64 + l31][ko];
        short8 b1 = *(const short8*)&Ws[ch * 64 + 32 + l31][ko];
        acc0 = __builtin_amdgcn_mfma_f32_32x32x16_bf16(a, b0, acc0, 0, 0, 0);
        acc1 = __builtin_amdgcn_mfma_f32_32x32x16_bf16(a, b1, acc1, 0, 0, 0);
    }

    int col0 = ch * 64 + l31;
    int col1 = col0 + 32;
    float bc0 = bconv[col0], bc1 = bconv[col1];
#pragma unroll
    for (int r = 0; r < 16; ++r) {
        float h0 = acc0[r] + bc0;
        float h1 = acc1[r] + bc1;
        float s = h0 + h1, ss = h0 * h0 + h1 * h1;
#pragma unroll
        for (int m = 1; m < 32; m <<= 1) {
            s += __shfl_xor(s, m, 64);
            ss += __shfl_xor(ss, m, 64);
        }
        if (l31 == 0) {
            int row_l = rh * 32 + (r & 3) + 8 * (r >> 2) + 4 * half;
            Ls[row_l][ch] = s;
            Lss[row_l][ch] = ss;
        }
    }
    __syncthreads();  // all MFMA done; Ls/Lss visible; Xs/Ws safe to overwrite

    if (Whb) {
#pragma unroll
        for (int i = 0; i < 4; ++i) {
            int cidx = tid + 256 * i;
            int r = cidx >> 4, koff = (cidx & 15) * 8;
            uint4 v = *(const uint4*)(Whb + (size_t)r * C + koff);
            *(uint4*)&Ws[r][koff] = v;
        }
    }

    float g0 = gamma[col0], g1 = gamma[col1];
    float be0 = beta[col0], be1 = beta[col1];
#pragma unroll
    for (int r = 0; r < 16; ++r) {
        int row_l = rh * 32 + (r & 3) + 8 * (r >> 2) + 4 * half;
        int rg = row0 + row_l;
        float s = Ls[row_l][0] + Ls[row_l][1];
        float ss = Lss[row_l][0] + Lss[row_l][1];
        float mu = s * (1.0f / 128.0f);
        float var = ss * (1.0f / 128.0f) - mu * mu;
        float rs = rsqrtf(var + 1e-5f);
        float h0 = acc0[r] + bc0;
        float h1 = acc1[r] + bc1;
        float o0 = fmaxf((h0 - mu) * rs * g0 + be0, 0.f);
        float o1 = fmaxf((h1 - mu) * rs * g1 + be1, 0.f);
        if (Whb) {
            Xs[row_l][col0] = f2b(o0);
            Xs[row_l][col1] = f2b(o1);
        } else if (rg < n) {
            Xout[(size_t)rg * C + col0] = f2b(o0);
            Xout[(size_t)rg * C + col1] = f2b(o1);
        }
    }

    if (Whb) {
        __syncthreads();  // act tile in Xs, Wh in Ws
        floatx16 hc;
#pragma unroll
        for (int i = 0; i < 16; ++i) hc[i] = 0.f;
        int m0 = rh * 32, n0 = ch * 32;
#pragma unroll
        for (int kc = 0; kc < C; kc += 16) {
            int ko = kc + half * 8;
            short8 a = *(const short8*)&Xs[m0 + l31][ko];
            short8 b = *(const short8*)&Ws[n0 + l31][ko];
            hc = __builtin_amdgcn_mfma_f32_32x32x16_bf16(a, b, hc, 0, 0, 0);
        }
        int oc = n0 + l31;
        float bhv = bh[oc];
#pragma unroll
        for (int r = 0; r < 16; ++r) {
            int row_l = m0 + (r & 3) + 8 * (r >> 2) + 4 * half;
            int rg = row0 + row_l;
            if (rg < n) out[(size_t)rg * 64 + oc] = hc[r] + bhv;
        }
    }
}

extern "C" void kernel_launch(void* const* d_in, const int* in_sizes, int n_in,
                              void* d_out, int out_size, void* d_ws, size_t ws_size,
                              hipStream_t stream) {
    const float* x = (const float*)d_in[0];
    const int* ei = (const int*)d_in[1];
    const float* Wn = (const float*)d_in[2];
    const float* Wr = (const float*)d_in[3];
    const float* bconv = (const float*)d_in[4];
    const float* gamma = (const float*)d_in[5];
    const float* beta = (const float*)d_in[6];
    const float* Wh = (const float*)d_in[7];
    const float* bh = (const float*)d_in[8];

    int N = in_sizes[0] / C;
    int E = in_sizes[1] / 2;
    int L = in_sizes[2] / (C * C);
    int num_seed = out_size / 64;
    int nchunks = (N + 255) / 256;

    char* ws = (char*)d_ws;
    size_t off = 0;
    auto alloc = [&](size_t bytes) {
        void* p = ws + off;
        off = (off + bytes + 255) & ~(size_t)255;
        return p;
    };
    int* deg = (int*)alloc((size_t)N * 4);
    int* row_start = (int*)alloc((size_t)(N + 1) * 4);
    int* cursor = (int*)alloc((size_t)N * 4);
    int* blocksum = (int*)alloc((size_t)nchunks * 4);
    int* esrc = (int*)alloc((size_t)E * 4);
    unsigned short* xb = (unsigned short*)alloc((size_t)N * C * 2);
    unsigned short* aggb = (unsigned short*)alloc((size_t)N * C * 2);
    unsigned short* xA = (unsigned short*)alloc((size_t)N * C * 2);
    unsigned short* xB = (unsigned short*)alloc((size_t)N * C * 2);
    unsigned short* Wnb = (unsigned short*)alloc((size_t)L * C * C * 2);
    unsigned short* Wrb = (unsigned short*)alloc((size_t)L * C * C * 2);
    unsigned short* Whb = (unsigned short*)alloc((size_t)64 * C * 2);

    const int* srcIdx = ei;
    const int* dstIdx = ei + E;

    int n4x = N * C / 4;
    int n4w = L * C * C / 4;
    int n4h = 64 * C / 4;
    int castBlocks = (n4x + 2 * n4w + n4h + 255) / 256;
    int degBlocks = (E + 255) / 256;

    hipMemsetAsync(deg, 0, (size_t)N * 4, stream);
    cast_count_kernel<<<castBlocks + degBlocks, 256, 0, stream>>>(
        x, xb, n4x, Wn, Wnb, Wr, Wrb, n4w, Wh, Whb, n4h, dstIdx, deg, E, castBlocks);
    scan_partial_kernel<<<nchunks, 256, 0, stream>>>(deg, blocksum, N);
    scan_scatter_kernel<<<nchunks, 256, 0, stream>>>(deg, blocksum, row_start, cursor, N, E);
    bucket_kernel<<<degBlocks, 256, 0, stream>>>(srcIdx, dstIdx, cursor, esrc, E);

    const unsigned short* cur = xb;
    unsigned short* bufs[2] = {xA, xB};
    for (int l = 0; l < L; ++l) {
        bool last = (l == L - 1);
        // layer-2+ outputs are only read for the first num_seed rows (head slice)
        int nl = last ? num_seed : N;
        unsigned short* nxt = bufs[l & 1];
        if (!last) {
            int aggThreads = ((nl + 3) / 4) * 64;
            aggregate_kernel<<<(aggThreads + 255) / 256, 256, 0, stream>>>(cur, row_start, esrc, aggb, nl);
        }
        gemm_mfma_ln_relu_kernel<<<(nl + 63) / 64, 256, 0, stream>>>(
            aggb, cur, row_start, esrc, last ? 1 : 0,
            Wnb + (size_t)l * C * C, Wrb + (size_t)l * C * C,
            bconv + (size_t)l * C, gamma + (size_t)l * C, beta + (size_t)l * C, nxt, nl,
            last ? Whb : (const unsigned short*)nullptr, bh, (float*)d_out);
        cur = nxt;
    }
}

// Round 11
// 224.879 us; speedup vs baseline: 1.0334x; 1.0334x over previous
//
#include <hip/hip_runtime.h>

#define C 128

typedef __attribute__((ext_vector_type(8))) short short8;
typedef __attribute__((ext_vector_type(16))) float floatx16;

__device__ __forceinline__ unsigned short f2b(float f) {
    union { float f; unsigned u; } v; v.f = f;
    unsigned u = v.u + 0x7fffu + ((v.u >> 16) & 1u);  // RNE
    return (unsigned short)(u >> 16);
}
__device__ __forceinline__ float b2f(unsigned short h) {
    union { unsigned u; float f; } v; v.u = ((unsigned)h) << 16;
    return v.f;
}
__device__ __forceinline__ void acc_pair(unsigned u, float& lo, float& hi) {
    union { unsigned u; float f; } a, b;
    a.u = u << 16;
    b.u = u & 0xffff0000u;
    lo += a.f;
    hi += b.f;
}

// ------- fused: fp32->bf16 casts (x, Wn, Wr, Wh) + degree histogram (one dispatch) -------
__global__ void cast_count_kernel(const float* __restrict__ x, unsigned short* __restrict__ xb, int n4x,
                                  const float* __restrict__ Wn, unsigned short* __restrict__ Wnb,
                                  const float* __restrict__ Wr, unsigned short* __restrict__ Wrb, int n4w,
                                  const float* __restrict__ Wh, unsigned short* __restrict__ Whb, int n4h,
                                  const int* __restrict__ dst, int* __restrict__ deg, int E,
                                  int castBlocks) {
    if ((int)blockIdx.x < castBlocks) {
        int i = blockIdx.x * blockDim.x + threadIdx.x;
        const float* in;
        unsigned short* out;
        int idx;
        if (i < n4x) { in = x; out = xb; idx = i; }
        else if (i < n4x + n4w) { in = Wn; out = Wnb; idx = i - n4x; }
        else if (i < n4x + 2 * n4w) { in = Wr; out = Wrb; idx = i - n4x - n4w; }
        else if (i < n4x + 2 * n4w + n4h) { in = Wh; out = Whb; idx = i - n4x - 2 * n4w; }
        else return;
        float4 v = ((const float4*)in)[idx];
        ushort4 o;
        o.x = f2b(v.x); o.y = f2b(v.y); o.z = f2b(v.z); o.w = f2b(v.w);
        ((ushort4*)out)[idx] = o;
    } else {
        int e = (blockIdx.x - castBlocks) * blockDim.x + threadIdx.x;
        if (e < E) atomicAdd(&deg[dst[e]], 1);
    }
}

// ---------------- scan phase 1: per-256-chunk sums ----------------
__global__ void scan_partial_kernel(const int* __restrict__ deg, int* __restrict__ blocksum, int n) {
    __shared__ int sm[256];
    int t = threadIdx.x;
    int i = blockIdx.x * 256 + t;
    sm[t] = (i < n) ? deg[i] : 0;
    __syncthreads();
#pragma unroll
    for (int off = 128; off > 0; off >>= 1) {
        if (t < off) sm[t] += sm[t + off];
        __syncthreads();
    }
    if (t == 0) blocksum[blockIdx.x] = sm[0];
}

// ---------------- scan phase 2 (merged): per-block offset + chunk scan + scatter ----------------
__global__ void scan_scatter_kernel(const int* __restrict__ deg, const int* __restrict__ blocksum,
                                    int* __restrict__ row_start, int* __restrict__ cursor,
                                    int n, int E) {
    __shared__ int osm[256];
    __shared__ int sm[256];
    int t = threadIdx.x, bid = blockIdx.x;
    int s = 0;
    for (int i = t; i < bid; i += 256) s += blocksum[i];
    osm[t] = s;
    __syncthreads();
#pragma unroll
    for (int off = 128; off > 0; off >>= 1) {
        if (t < off) osm[t] += osm[t + off];
        __syncthreads();
    }
    int boff = osm[0];
    int i = bid * 256 + t;
    int d = (i < n) ? deg[i] : 0;
    sm[t] = d;
    __syncthreads();
    for (int off = 1; off < 256; off <<= 1) {
        int v = (t >= off) ? sm[t - off] : 0;
        __syncthreads();
        sm[t] += v;
        __syncthreads();
    }
    int excl = sm[t] - d + boff;
    if (i < n) {
        row_start[i] = excl;
        cursor[i] = excl;
    }
    if (i == n - 1) row_start[n] = E;
}

// ---------------- bucket edges by dst (counting sort) ----------------
__global__ void bucket_kernel(const int* __restrict__ src, const int* __restrict__ dst,
                              int* __restrict__ cursor, int* __restrict__ esrc, int E) {
    int e = blockIdx.x * blockDim.x + threadIdx.x;
    if (e < E) {
        int d = dst[e];
        int p = atomicAdd(&cursor[d], 1);
        esrc[p] = src[e];
    }
}

// ---------------- mean aggregation: QUARTER-wave per node (R9 known-good, 4-deep ILP) ----------------
__global__ void aggregate_kernel(const unsigned short* __restrict__ xb, const int* __restrict__ row_start,
                                 const int* __restrict__ esrc,
                                 unsigned short* __restrict__ agg, int n) {
    int wid = (blockIdx.x * blockDim.x + threadIdx.x) >> 6;
    int lane = threadIdx.x & 63;
    int q = lane >> 4, l16 = lane & 15;
    int qb = lane & 48;
    int node = wid * 4 + q;
    if (node >= n) return;

    int beg = row_start[node];
    int end = row_start[node + 1];
    size_t choff = (size_t)l16 * 8;

    float a0 = 0.f, a1 = 0.f, a2 = 0.f, a3 = 0.f, a4 = 0.f, a5 = 0.f, a6 = 0.f, a7 = 0.f;

    for (int base = beg; base < end; base += 16) {
        int cnt = min(end - base, 16);
        int e_val = (base + l16 < end) ? esrc[base + l16] : 0;
        int j = 0;
        for (; j + 4 <= cnt; j += 4) {
            int s0 = __shfl(e_val, qb | j, 64);
            int s1 = __shfl(e_val, qb | (j + 1), 64);
            int s2 = __shfl(e_val, qb | (j + 2), 64);
            int s3 = __shfl(e_val, qb | (j + 3), 64);
            uint4 v0 = *(const uint4*)(xb + (size_t)s0 * C + choff);
            uint4 v1 = *(const uint4*)(xb + (size_t)s1 * C + choff);
            uint4 v2 = *(const uint4*)(xb + (size_t)s2 * C + choff);
            uint4 v3 = *(const uint4*)(xb + (size_t)s3 * C + choff);
            acc_pair(v0.x, a0, a1); acc_pair(v0.y, a2, a3); acc_pair(v0.z, a4, a5); acc_pair(v0.w, a6, a7);
            acc_pair(v1.x, a0, a1); acc_pair(v1.y, a2, a3); acc_pair(v1.z, a4, a5); acc_pair(v1.w, a6, a7);
            acc_pair(v2.x, a0, a1); acc_pair(v2.y, a2, a3); acc_pair(v2.z, a4, a5); acc_pair(v2.w, a6, a7);
            acc_pair(v3.x, a0, a1); acc_pair(v3.y, a2, a3); acc_pair(v3.z, a4, a5); acc_pair(v3.w, a6, a7);
        }
        for (; j < cnt; ++j) {
            int s0 = __shfl(e_val, qb | j, 64);
            uint4 v0 = *(const uint4*)(xb + (size_t)s0 * C + choff);
            acc_pair(v0.x, a0, a1); acc_pair(v0.y, a2, a3); acc_pair(v0.z, a4, a5); acc_pair(v0.w, a6, a7);
        }
    }

    float sc = 1.0f / fmaxf((float)(end - beg), 1.0f);
    uint4 o;
    o.x = ((unsigned)f2b(a1 * sc) << 16) | (unsigned)f2b(a0 * sc);
    o.y = ((unsigned)f2b(a3 * sc) << 16) | (unsigned)f2b(a2 * sc);
    o.z = ((unsigned)f2b(a5 * sc) << 16) | (unsigned)f2b(a4 * sc);
    o.w = ((unsigned)f2b(a7 * sc) << 16) | (unsigned)f2b(a6 * sc);
    *(uint4*)(agg + (size_t)node * C + choff) = o;
}

// ---- MFMA GEMM, 64-row blocks (R9 known-good phase-loop structure, NO prefetch) ----
// + LN + ReLU, optional fused head (Whb != nullptr), optional in-kernel gather (gather!=0,
// used only for the tiny 16-block final layer so its aggregate dispatch disappears).
__launch_bounds__(256)
__global__ void gemm_mfma_ln_relu_kernel(const unsigned short* __restrict__ Aagg,
                                         const unsigned short* __restrict__ Xin,
                                         const int* __restrict__ row_start,
                                         const int* __restrict__ esrc, int gather,
                                         const unsigned short* __restrict__ Wn,
                                         const unsigned short* __restrict__ Wr,
                                         const float* __restrict__ bconv, const float* __restrict__ gamma,
                                         const float* __restrict__ beta, unsigned short* __restrict__ Xout,
                                         int n,
                                         const unsigned short* __restrict__ Whb,
                                         const float* __restrict__ bh, float* __restrict__ out) {
    __shared__ unsigned short Xs[64][136];
    __shared__ unsigned short Ws[128][136];
    __shared__ float Ls[64][2];
    __shared__ float Lss[64][2];

    int tid = threadIdx.x;
    int wave = tid >> 6, lane = tid & 63;
    int rh = wave & 1, ch = wave >> 1;
    int l31 = lane & 31, half = lane >> 5;
    int row0 = blockIdx.x * 64;

    floatx16 acc0, acc1;
#pragma unroll
    for (int i = 0; i < 16; ++i) { acc0[i] = 0.f; acc1[i] = 0.f; }

#pragma unroll
    for (int phase = 0; phase < 2; ++phase) {
        const unsigned short* Ap = phase ? Xin : Aagg;
        const unsigned short* Wp = phase ? Wr : Wn;
        __syncthreads();
        if (phase == 0 && gather) {
            // quarter-wave gather of the agg tile straight into Xs (final layer only)
            int q = lane >> 4, l16 = lane & 15;
            int qb = lane & 48;
            size_t choff = (size_t)l16 * 8;
#pragma unroll
            for (int rnd = 0; rnd < 4; ++rnd) {
                int rl = wave * 16 + rnd * 4 + q;
                int node = row0 + rl;
                if (node < n) {
                    int beg = row_start[node];
                    int end = row_start[node + 1];
                    float a0 = 0.f, a1 = 0.f, a2 = 0.f, a3 = 0.f, a4 = 0.f, a5 = 0.f, a6 = 0.f, a7 = 0.f;
                    for (int base = beg; base < end; base += 16) {
                        int cnt = min(end - base, 16);
                        int e_val = (base + l16 < end) ? esrc[base + l16] : 0;
                        int j = 0;
                        for (; j + 4 <= cnt; j += 4) {
                            int s0 = __shfl(e_val, qb | j, 64);
                            int s1 = __shfl(e_val, qb | (j + 1), 64);
                            int s2 = __shfl(e_val, qb | (j + 2), 64);
                            int s3 = __shfl(e_val, qb | (j + 3), 64);
                            uint4 v0 = *(const uint4*)(Xin + (size_t)s0 * C + choff);
                            uint4 v1 = *(const uint4*)(Xin + (size_t)s1 * C + choff);
                            uint4 v2 = *(const uint4*)(Xin + (size_t)s2 * C + choff);
                            uint4 v3 = *(const uint4*)(Xin + (size_t)s3 * C + choff);
                            acc_pair(v0.x, a0, a1); acc_pair(v0.y, a2, a3); acc_pair(v0.z, a4, a5); acc_pair(v0.w, a6, a7);
                            acc_pair(v1.x, a0, a1); acc_pair(v1.y, a2, a3); acc_pair(v1.z, a4, a5); acc_pair(v1.w, a6, a7);
                            acc_pair(v2.x, a0, a1); acc_pair(v2.y, a2, a3); acc_pair(v2.z, a4, a5); acc_pair(v2.w, a6, a7);
                            acc_pair(v3.x, a0, a1); acc_pair(v3.y, a2, a3); acc_pair(v3.z, a4, a5); acc_pair(v3.w, a6, a7);
                        }
                        for (; j < cnt; ++j) {
                            int s0 = __shfl(e_val, qb | j, 64);
                            uint4 v0 = *(const uint4*)(Xin + (size_t)s0 * C + choff);
                            acc_pair(v0.x, a0, a1); acc_pair(v0.y, a2, a3); acc_pair(v0.z, a4, a5); acc_pair(v0.w, a6, a7);
                        }
                    }
                    float sc = 1.0f / fmaxf((float)(end - beg), 1.0f);
                    uint4 o;
                    o.x = ((unsigned)f2b(a1 * sc) << 16) | (unsigned)f2b(a0 * sc);
                    o.y = ((unsigned)f2b(a3 * sc) << 16) | (unsigned)f2b(a2 * sc);
                    o.z = ((unsigned)f2b(a5 * sc) << 16) | (unsigned)f2b(a4 * sc);
                    o.w = ((unsigned)f2b(a7 * sc) << 16) | (unsigned)f2b(a6 * sc);
                    *(uint4*)&Xs[rl][l16 * 8] = o;
                } else {
                    *(uint4*)&Xs[rl][l16 * 8] = make_uint4(0u, 0u, 0u, 0u);
                }
            }
        } else {
#pragma unroll
            for (int i = 0; i < 4; ++i) {
                int cidx = tid + 256 * i;
                int r = cidx >> 4, koff = (cidx & 15) * 8;
                uint4 v = make_uint4(0u, 0u, 0u, 0u);
                int rg = row0 + r;
                if (rg < n) v = *(const uint4*)(Ap + (size_t)rg * C + koff);
                *(uint4*)&Xs[r][koff] = v;
            }
        }
#pragma unroll
        for (int i = 0; i < 8; ++i) {
            int cidx = tid + 256 * i;
            int r = cidx >> 4, koff = (cidx & 15) * 8;
            uint4 v = *(const uint4*)(Wp + (size_t)r * C + koff);
            *(uint4*)&Ws[r][koff] = v;
        }
        __syncthreads();
#pragma unroll
        for (int kc = 0; kc < C; kc += 16) {
            int ko = kc + half * 8;
            short8 a = *(const short8*)&Xs[rh * 32 + l31][ko];
            short8 b0 = *(const short8*)&Ws[ch * 64 + l31][ko];
            short8 b1 = *(const short8*)&Ws[ch * 64 + 32 + l31][ko];
            acc0 = __builtin_amdgcn_mfma_f32_32x32x16_bf16(a, b0, acc0, 0, 0, 0);
            acc1 = __builtin_amdgcn_mfma_f32_32x32x16_bf16(a, b1, acc1, 0, 0, 0);
        }
    }

    int col0 = ch * 64 + l31;
    int col1 = col0 + 32;
    float bc0 = bconv[col0], bc1 = bconv[col1];
#pragma unroll
    for (int r = 0; r < 16; ++r) {
        float h0 = acc0[r] + bc0;
        float h1 = acc1[r] + bc1;
        float s = h0 + h1, ss = h0 * h0 + h1 * h1;
#pragma unroll
        for (int m = 1; m < 32; m <<= 1) {
            s += __shfl_xor(s, m, 64);
            ss += __shfl_xor(ss, m, 64);
        }
        if (l31 == 0) {
            int row_l = rh * 32 + (r & 3) + 8 * (r >> 2) + 4 * half;
            Ls[row_l][ch] = s;
            Lss[row_l][ch] = ss;
        }
    }
    __syncthreads();  // all MFMA done; Ls/Lss visible; Xs/Ws safe to overwrite

    // final layer: stage Wh (64 x 128 bf16) into Ws (safe: phase-1 MFMA is done)
    if (Whb) {
#pragma unroll
        for (int i = 0; i < 4; ++i) {
            int cidx = tid + 256 * i;
            int r = cidx >> 4, koff = (cidx & 15) * 8;
            uint4 v = *(const uint4*)(Whb + (size_t)r * C + koff);
            *(uint4*)&Ws[r][koff] = v;
        }
    }

    float g0 = gamma[col0], g1 = gamma[col1];
    float be0 = beta[col0], be1 = beta[col1];
#pragma unroll
    for (int r = 0; r < 16; ++r) {
        int row_l = rh * 32 + (r & 3) + 8 * (r >> 2) + 4 * half;
        int rg = row0 + row_l;
        float s = Ls[row_l][0] + Ls[row_l][1];
        float ss = Lss[row_l][0] + Lss[row_l][1];
        float mu = s * (1.0f / 128.0f);
        float var = ss * (1.0f / 128.0f) - mu * mu;
        float rs = rsqrtf(var + 1e-5f);
        float h0 = acc0[r] + bc0;
        float h1 = acc1[r] + bc1;
        float o0 = fmaxf((h0 - mu) * rs * g0 + be0, 0.f);
        float o1 = fmaxf((h1 - mu) * rs * g1 + be1, 0.f);
        if (Whb) {
            Xs[row_l][col0] = f2b(o0);
            Xs[row_l][col1] = f2b(o1);
        } else if (rg < n) {
            Xout[(size_t)rg * C + col0] = f2b(o0);
            Xout[(size_t)rg * C + col1] = f2b(o1);
        }
    }

    if (Whb) {
        __syncthreads();  // act tile in Xs, Wh in Ws
        floatx16 hc;
#pragma unroll
        for (int i = 0; i < 16; ++i) hc[i] = 0.f;
        int m0 = rh * 32, n0 = ch * 32;
#pragma unroll
        for (int kc = 0; kc < C; kc += 16) {
            int ko = kc + half * 8;
            short8 a = *(const short8*)&Xs[m0 + l31][ko];
            short8 b = *(const short8*)&Ws[n0 + l31][ko];
            hc = __builtin_amdgcn_mfma_f32_32x32x16_bf16(a, b, hc, 0, 0, 0);
        }
        int oc = n0 + l31;
        float bhv = bh[oc];
#pragma unroll
        for (int r = 0; r < 16; ++r) {
            int row_l = m0 + (r & 3) + 8 * (r >> 2) + 4 * half;
            int rg = row0 + row_l;
            if (rg < n) out[(size_t)rg * 64 + oc] = hc[r] + bhv;
        }
    }
}

extern "C" void kernel_launch(void* const* d_in, const int* in_sizes, int n_in,
                              void* d_out, int out_size, void* d_ws, size_t ws_size,
                              hipStream_t stream) {
    const float* x = (const float*)d_in[0];
    const int* ei = (const int*)d_in[1];
    const float* Wn = (const float*)d_in[2];
    const float* Wr = (const float*)d_in[3];
    const float* bconv = (const float*)d_in[4];
    const float* gamma = (const float*)d_in[5];
    const float* beta = (const float*)d_in[6];
    const float* Wh = (const float*)d_in[7];
    const float* bh = (const float*)d_in[8];

    int N = in_sizes[0] / C;
    int E = in_sizes[1] / 2;
    int L = in_sizes[2] / (C * C);
    int num_seed = out_size / 64;
    int nchunks = (N + 255) / 256;

    char* ws = (char*)d_ws;
    size_t off = 0;
    auto alloc = [&](size_t bytes) {
        void* p = ws + off;
        off = (off + bytes + 255) & ~(size_t)255;
        return p;
    };
    int* deg = (int*)alloc((size_t)N * 4);
    int* row_start = (int*)alloc((size_t)(N + 1) * 4);
    int* cursor = (int*)alloc((size_t)N * 4);
    int* blocksum = (int*)alloc((size_t)nchunks * 4);
    int* esrc = (int*)alloc((size_t)E * 4);
    unsigned short* xb = (unsigned short*)alloc((size_t)N * C * 2);
    unsigned short* aggb = (unsigned short*)alloc((size_t)N * C * 2);
    unsigned short* xA = (unsigned short*)alloc((size_t)N * C * 2);
    unsigned short* xB = (unsigned short*)alloc((size_t)N * C * 2);
    unsigned short* Wnb = (unsigned short*)alloc((size_t)L * C * C * 2);
    unsigned short* Wrb = (unsigned short*)alloc((size_t)L * C * C * 2);
    unsigned short* Whb = (unsigned short*)alloc((size_t)64 * C * 2);

    const int* srcIdx = ei;
    const int* dstIdx = ei + E;

    int n4x = N * C / 4;
    int n4w = L * C * C / 4;
    int n4h = 64 * C / 4;
    int castBlocks = (n4x + 2 * n4w + n4h + 255) / 256;
    int degBlocks = (E + 255) / 256;

    hipMemsetAsync(deg, 0, (size_t)N * 4, stream);
    cast_count_kernel<<<castBlocks + degBlocks, 256, 0, stream>>>(
        x, xb, n4x, Wn, Wnb, Wr, Wrb, n4w, Wh, Whb, n4h, dstIdx, deg, E, castBlocks);
    scan_partial_kernel<<<nchunks, 256, 0, stream>>>(deg, blocksum, N);
    scan_scatter_kernel<<<nchunks, 256, 0, stream>>>(deg, blocksum, row_start, cursor, N, E);
    bucket_kernel<<<degBlocks, 256, 0, stream>>>(srcIdx, dstIdx, cursor, esrc, E);

    const unsigned short* cur = xb;
    unsigned short* bufs[2] = {xA, xB};
    for (int l = 0; l < L; ++l) {
        bool last = (l == L - 1);
        // layer-2+ outputs are only read for the first num_seed rows (head slice)
        int nl = last ? num_seed : N;
        unsigned short* nxt = bufs[l & 1];
        if (!last) {
            int aggThreads = ((nl + 3) / 4) * 64;
            aggregate_kernel<<<(aggThreads + 255) / 256, 256, 0, stream>>>(cur, row_start, esrc, aggb, nl);
        }
        gemm_mfma_ln_relu_kernel<<<(nl + 63) / 64, 256, 0, stream>>>(
            aggb, cur, row_start, esrc, last ? 1 : 0,
            Wnb + (size_t)l * C * C, Wrb + (size_t)l * C * C,
            bconv + (size_t)l * C, gamma + (size_t)l * C, beta + (size_t)l * C, nxt, nl,
            last ? Whb : (const unsigned short*)nullptr, bh, (float*)d_out);
        cur = nxt;
    }
}

// Round 12
// 218.186 us; speedup vs baseline: 1.0651x; 1.0307x over previous
//
#include <hip/hip_runtime.h>

#define C 128

typedef __attribute__((ext_vector_type(8))) short short8;
typedef __attribute__((ext_vector_type(16))) float floatx16;

__device__ __forceinline__ unsigned short f2b(float f) {
    union { float f; unsigned u; } v; v.f = f;
    unsigned u = v.u + 0x7fffu + ((v.u >> 16) & 1u);  // RNE
    return (unsigned short)(u >> 16);
}
__device__ __forceinline__ float b2f(unsigned short h) {
    union { unsigned u; float f; } v; v.u = ((unsigned)h) << 16;
    return v.f;
}
__device__ __forceinline__ void acc_pair(unsigned u, float& lo, float& hi) {
    union { unsigned u; float f; } a, b;
    a.u = u << 16;
    b.u = u & 0xffff0000u;
    lo += a.f;
    hi += b.f;
}

// ------- fused: fp32->bf16 casts (x, Wn, Wr, Wh) + degree histogram (one dispatch) -------
__global__ void cast_count_kernel(const float* __restrict__ x, unsigned short* __restrict__ xb, int n4x,
                                  const float* __restrict__ Wn, unsigned short* __restrict__ Wnb,
                                  const float* __restrict__ Wr, unsigned short* __restrict__ Wrb, int n4w,
                                  const float* __restrict__ Wh, unsigned short* __restrict__ Whb, int n4h,
                                  const int* __restrict__ dst, int* __restrict__ deg, int E,
                                  int castBlocks) {
    if ((int)blockIdx.x < castBlocks) {
        int i = blockIdx.x * blockDim.x + threadIdx.x;
        const float* in;
        unsigned short* out;
        int idx;
        if (i < n4x) { in = x; out = xb; idx = i; }
        else if (i < n4x + n4w) { in = Wn; out = Wnb; idx = i - n4x; }
        else if (i < n4x + 2 * n4w) { in = Wr; out = Wrb; idx = i - n4x - n4w; }
        else if (i < n4x + 2 * n4w + n4h) { in = Wh; out = Whb; idx = i - n4x - 2 * n4w; }
        else return;
        float4 v = ((const float4*)in)[idx];
        ushort4 o;
        o.x = f2b(v.x); o.y = f2b(v.y); o.z = f2b(v.z); o.w = f2b(v.w);
        ((ushort4*)out)[idx] = o;
    } else {
        int e = (blockIdx.x - castBlocks) * blockDim.x + threadIdx.x;
        if (e < E) atomicAdd(&deg[dst[e]], 1);
    }
}

// ---------------- scan phase 1: per-256-chunk sums ----------------
__global__ void scan_partial_kernel(const int* __restrict__ deg, int* __restrict__ blocksum, int n) {
    __shared__ int sm[256];
    int t = threadIdx.x;
    int i = blockIdx.x * 256 + t;
    sm[t] = (i < n) ? deg[i] : 0;
    __syncthreads();
#pragma unroll
    for (int off = 128; off > 0; off >>= 1) {
        if (t < off) sm[t] += sm[t + off];
        __syncthreads();
    }
    if (t == 0) blocksum[blockIdx.x] = sm[0];
}

// ---------------- scan phase 2 (merged): per-block offset + chunk scan + scatter ----------------
__global__ void scan_scatter_kernel(const int* __restrict__ deg, const int* __restrict__ blocksum,
                                    int* __restrict__ row_start, int* __restrict__ cursor,
                                    int n, int E) {
    __shared__ int osm[256];
    __shared__ int sm[256];
    int t = threadIdx.x, bid = blockIdx.x;
    int s = 0;
    for (int i = t; i < bid; i += 256) s += blocksum[i];
    osm[t] = s;
    __syncthreads();
#pragma unroll
    for (int off = 128; off > 0; off >>= 1) {
        if (t < off) osm[t] += osm[t + off];
        __syncthreads();
    }
    int boff = osm[0];
    int i = bid * 256 + t;
    int d = (i < n) ? deg[i] : 0;
    sm[t] = d;
    __syncthreads();
    for (int off = 1; off < 256; off <<= 1) {
        int v = (t >= off) ? sm[t - off] : 0;
        __syncthreads();
        sm[t] += v;
        __syncthreads();
    }
    int excl = sm[t] - d + boff;
    if (i < n) {
        row_start[i] = excl;
        cursor[i] = excl;
    }
    if (i == n - 1) row_start[n] = E;
}

// ---------------- bucket edges by dst (counting sort) ----------------
__global__ void bucket_kernel(const int* __restrict__ src, const int* __restrict__ dst,
                              int* __restrict__ cursor, int* __restrict__ esrc, int E) {
    int e = blockIdx.x * blockDim.x + threadIdx.x;
    if (e < E) {
        int d = dst[e];
        int p = atomicAdd(&cursor[d], 1);
        esrc[p] = src[e];
    }
}

// ---------------- mean aggregation: QUARTER-wave per node (4-deep row ILP) ----------------
__global__ void aggregate_kernel(const unsigned short* __restrict__ xb, const int* __restrict__ row_start,
                                 const int* __restrict__ esrc,
                                 unsigned short* __restrict__ agg, int n) {
    int wid = (blockIdx.x * blockDim.x + threadIdx.x) >> 6;
    int lane = threadIdx.x & 63;
    int q = lane >> 4, l16 = lane & 15;
    int qb = lane & 48;
    int node = wid * 4 + q;
    if (node >= n) return;

    int beg = row_start[node];
    int end = row_start[node + 1];
    size_t choff = (size_t)l16 * 8;

    float a0 = 0.f, a1 = 0.f, a2 = 0.f, a3 = 0.f, a4 = 0.f, a5 = 0.f, a6 = 0.f, a7 = 0.f;

    for (int base = beg; base < end; base += 16) {
        int cnt = min(end - base, 16);
        int e_val = (base + l16 < end) ? esrc[base + l16] : 0;
        int j = 0;
        for (; j + 4 <= cnt; j += 4) {
            int s0 = __shfl(e_val, qb | j, 64);
            int s1 = __shfl(e_val, qb | (j + 1), 64);
            int s2 = __shfl(e_val, qb | (j + 2), 64);
            int s3 = __shfl(e_val, qb | (j + 3), 64);
            uint4 v0 = *(const uint4*)(xb + (size_t)s0 * C + choff);
            uint4 v1 = *(const uint4*)(xb + (size_t)s1 * C + choff);
            uint4 v2 = *(const uint4*)(xb + (size_t)s2 * C + choff);
            uint4 v3 = *(const uint4*)(xb + (size_t)s3 * C + choff);
            acc_pair(v0.x, a0, a1); acc_pair(v0.y, a2, a3); acc_pair(v0.z, a4, a5); acc_pair(v0.w, a6, a7);
            acc_pair(v1.x, a0, a1); acc_pair(v1.y, a2, a3); acc_pair(v1.z, a4, a5); acc_pair(v1.w, a6, a7);
            acc_pair(v2.x, a0, a1); acc_pair(v2.y, a2, a3); acc_pair(v2.z, a4, a5); acc_pair(v2.w, a6, a7);
            acc_pair(v3.x, a0, a1); acc_pair(v3.y, a2, a3); acc_pair(v3.z, a4, a5); acc_pair(v3.w, a6, a7);
        }
        for (; j < cnt; ++j) {
            int s0 = __shfl(e_val, qb | j, 64);
            uint4 v0 = *(const uint4*)(xb + (size_t)s0 * C + choff);
            acc_pair(v0.x, a0, a1); acc_pair(v0.y, a2, a3); acc_pair(v0.z, a4, a5); acc_pair(v0.w, a6, a7);
        }
    }

    float sc = 1.0f / fmaxf((float)(end - beg), 1.0f);
    uint4 o;
    o.x = ((unsigned)f2b(a1 * sc) << 16) | (unsigned)f2b(a0 * sc);
    o.y = ((unsigned)f2b(a3 * sc) << 16) | (unsigned)f2b(a2 * sc);
    o.z = ((unsigned)f2b(a5 * sc) << 16) | (unsigned)f2b(a4 * sc);
    o.w = ((unsigned)f2b(a7 * sc) << 16) | (unsigned)f2b(a6 * sc);
    *(uint4*)(agg + (size_t)node * C + choff) = o;
}

// ---- MFMA GEMM, 64-row blocks (h = agg@Wn^T + x@Wr^T + b) + LN + ReLU (+fused head) ----
// R9 known-good structure: block = 64 rows x 128 cols, 4 waves, one tile per block.
// Wave w: rows (w&1)*32, cols (w>>1)*64 via two mfma_32x32x16. If Whb != nullptr (final
// layer), post-LN activations go to Xs (LDS) and the block finishes act@Wh^T + bh -> out.
__launch_bounds__(256)
__global__ void gemm_mfma_ln_relu_kernel(const unsigned short* __restrict__ Aagg,
                                         const unsigned short* __restrict__ Xin,
                                         const unsigned short* __restrict__ Wn,
                                         const unsigned short* __restrict__ Wr,
                                         const float* __restrict__ bconv, const float* __restrict__ gamma,
                                         const float* __restrict__ beta, unsigned short* __restrict__ Xout,
                                         int n,
                                         const unsigned short* __restrict__ Whb,
                                         const float* __restrict__ bh, float* __restrict__ out) {
    __shared__ unsigned short Xs[64][136];
    __shared__ unsigned short Ws[128][136];
    __shared__ float Ls[64][2];
    __shared__ float Lss[64][2];

    int tid = threadIdx.x;
    int wave = tid >> 6, lane = tid & 63;
    int rh = wave & 1, ch = wave >> 1;
    int l31 = lane & 31, half = lane >> 5;
    int row0 = blockIdx.x * 64;

    floatx16 acc0, acc1;
#pragma unroll
    for (int i = 0; i < 16; ++i) { acc0[i] = 0.f; acc1[i] = 0.f; }

#pragma unroll
    for (int phase = 0; phase < 2; ++phase) {
        const unsigned short* Ap = phase ? Xin : Aagg;
        const unsigned short* Wp = phase ? Wr : Wn;
        __syncthreads();
#pragma unroll
        for (int i = 0; i < 4; ++i) {
            int cidx = tid + 256 * i;
            int r = cidx >> 4, koff = (cidx & 15) * 8;
            uint4 v = make_uint4(0u, 0u, 0u, 0u);
            int rg = row0 + r;
            if (rg < n) v = *(const uint4*)(Ap + (size_t)rg * C + koff);
            *(uint4*)&Xs[r][koff] = v;
        }
#pragma unroll
        for (int i = 0; i < 8; ++i) {
            int cidx = tid + 256 * i;
            int r = cidx >> 4, koff = (cidx & 15) * 8;
            uint4 v = *(const uint4*)(Wp + (size_t)r * C + koff);
            *(uint4*)&Ws[r][koff] = v;
        }
        __syncthreads();
#pragma unroll
        for (int kc = 0; kc < C; kc += 16) {
            int ko = kc + half * 8;
            short8 a = *(const short8*)&Xs[rh * 32 + l31][ko];
            short8 b0 = *(const short8*)&Ws[ch * 64 + l31][ko];
            short8 b1 = *(const short8*)&Ws[ch * 64 + 32 + l31][ko];
            acc0 = __builtin_amdgcn_mfma_f32_32x32x16_bf16(a, b0, acc0, 0, 0, 0);
            acc1 = __builtin_amdgcn_mfma_f32_32x32x16_bf16(a, b1, acc1, 0, 0, 0);
        }
    }

    int col0 = ch * 64 + l31;
    int col1 = col0 + 32;
    float bc0 = bconv[col0], bc1 = bconv[col1];
#pragma unroll
    for (int r = 0; r < 16; ++r) {
        float h0 = acc0[r] + bc0;
        float h1 = acc1[r] + bc1;
        float s = h0 + h1, ss = h0 * h0 + h1 * h1;
#pragma unroll
        for (int m = 1; m < 32; m <<= 1) {
            s += __shfl_xor(s, m, 64);
            ss += __shfl_xor(ss, m, 64);
        }
        if (l31 == 0) {
            int row_l = rh * 32 + (r & 3) + 8 * (r >> 2) + 4 * half;
            Ls[row_l][ch] = s;
            Lss[row_l][ch] = ss;
        }
    }
    __syncthreads();  // all MFMA done; Ls/Lss visible; Xs/Ws now safe to overwrite

    // final layer: stage Wh (64 x 128 bf16) into Ws (safe: phase-1 MFMA is done)
    if (Whb) {
#pragma unroll
        for (int i = 0; i < 4; ++i) {
            int cidx = tid + 256 * i;
            int r = cidx >> 4, koff = (cidx & 15) * 8;
            uint4 v = *(const uint4*)(Whb + (size_t)r * C + koff);
            *(uint4*)&Ws[r][koff] = v;
        }
    }

    float g0 = gamma[col0], g1 = gamma[col1];
    float be0 = beta[col0], be1 = beta[col1];
#pragma unroll
    for (int r = 0; r < 16; ++r) {
        int row_l = rh * 32 + (r & 3) + 8 * (r >> 2) + 4 * half;
        int rg = row0 + row_l;
        float s = Ls[row_l][0] + Ls[row_l][1];
        float ss = Lss[row_l][0] + Lss[row_l][1];
        float mu = s * (1.0f / 128.0f);
        float var = ss * (1.0f / 128.0f) - mu * mu;
        float rs = rsqrtf(var + 1e-5f);
        float h0 = acc0[r] + bc0;
        float h1 = acc1[r] + bc1;
        float o0 = fmaxf((h0 - mu) * rs * g0 + be0, 0.f);
        float o1 = fmaxf((h1 - mu) * rs * g1 + be1, 0.f);
        if (Whb) {
            Xs[row_l][col0] = f2b(o0);
            Xs[row_l][col1] = f2b(o1);
        } else if (rg < n) {
            Xout[(size_t)rg * C + col0] = f2b(o0);
            Xout[(size_t)rg * C + col1] = f2b(o1);
        }
    }

    if (Whb) {
        __syncthreads();  // act tile in Xs, Wh in Ws
        floatx16 hc;
#pragma unroll
        for (int i = 0; i < 16; ++i) hc[i] = 0.f;
        int m0 = rh * 32, n0 = ch * 32;
#pragma unroll
        for (int kc = 0; kc < C; kc += 16) {
            int ko = kc + half * 8;
            short8 a = *(const short8*)&Xs[m0 + l31][ko];
            short8 b = *(const short8*)&Ws[n0 + l31][ko];
            hc = __builtin_amdgcn_mfma_f32_32x32x16_bf16(a, b, hc, 0, 0, 0);
        }
        int oc = n0 + l31;
        float bhv = bh[oc];
#pragma unroll
        for (int r = 0; r < 16; ++r) {
            int row_l = m0 + (r & 3) + 8 * (r >> 2) + 4 * half;
            int rg = row0 + row_l;
            if (rg < n) out[(size_t)rg * 64 + oc] = hc[r] + bhv;
        }
    }
}

extern "C" void kernel_launch(void* const* d_in, const int* in_sizes, int n_in,
                              void* d_out, int out_size, void* d_ws, size_t ws_size,
                              hipStream_t stream) {
    const float* x = (const float*)d_in[0];
    const int* ei = (const int*)d_in[1];
    const float* Wn = (const float*)d_in[2];
    const float* Wr = (const float*)d_in[3];
    const float* bconv = (const float*)d_in[4];
    const float* gamma = (const float*)d_in[5];
    const float* beta = (const float*)d_in[6];
    const float* Wh = (const float*)d_in[7];
    const float* bh = (const float*)d_in[8];

    int N = in_sizes[0] / C;
    int E = in_sizes[1] / 2;
    int L = in_sizes[2] / (C * C);
    int num_seed = out_size / 64;
    int nchunks = (N + 255) / 256;

    char* ws = (char*)d_ws;
    size_t off = 0;
    auto alloc = [&](size_t bytes) {
        void* p = ws + off;
        off = (off + bytes + 255) & ~(size_t)255;
        return p;
    };
    int* deg = (int*)alloc((size_t)N * 4);
    int* row_start = (int*)alloc((size_t)(N + 1) * 4);
    int* cursor = (int*)alloc((size_t)N * 4);
    int* blocksum = (int*)alloc((size_t)nchunks * 4);
    int* esrc = (int*)alloc((size_t)E * 4);
    unsigned short* xb = (unsigned short*)alloc((size_t)N * C * 2);
    unsigned short* aggb = (unsigned short*)alloc((size_t)N * C * 2);
    unsigned short* xA = (unsigned short*)alloc((size_t)N * C * 2);
    unsigned short* xB = (unsigned short*)alloc((size_t)N * C * 2);
    unsigned short* Wnb = (unsigned short*)alloc((size_t)L * C * C * 2);
    unsigned short* Wrb = (unsigned short*)alloc((size_t)L * C * C * 2);
    unsigned short* Whb = (unsigned short*)alloc((size_t)64 * C * 2);

    const int* srcIdx = ei;
    const int* dstIdx = ei + E;

    int n4x = N * C / 4;
    int n4w = L * C * C / 4;
    int n4h = 64 * C / 4;
    int castBlocks = (n4x + 2 * n4w + n4h + 255) / 256;
    int degBlocks = (E + 255) / 256;

    hipMemsetAsync(deg, 0, (size_t)N * 4, stream);
    cast_count_kernel<<<castBlocks + degBlocks, 256, 0, stream>>>(
        x, xb, n4x, Wn, Wnb, Wr, Wrb, n4w, Wh, Whb, n4h, dstIdx, deg, E, castBlocks);
    scan_partial_kernel<<<nchunks, 256, 0, stream>>>(deg, blocksum, N);
    scan_scatter_kernel<<<nchunks, 256, 0, stream>>>(deg, blocksum, row_start, cursor, N, E);
    bucket_kernel<<<degBlocks, 256, 0, stream>>>(srcIdx, dstIdx, cursor, esrc, E);

    const unsigned short* cur = xb;
    unsigned short* bufs[2] = {xA, xB};
    for (int l = 0; l < L; ++l) {
        bool last = (l == L - 1);
        // layer-2+ outputs are only read for the first num_seed rows (head slice)
        int nl = last ? num_seed : N;
        unsigned short* nxt = bufs[l & 1];
        int aggThreads = ((nl + 3) / 4) * 64;
        aggregate_kernel<<<(aggThreads + 255) / 256, 256, 0, stream>>>(cur, row_start, esrc, aggb, nl);
        gemm_mfma_ln_relu_kernel<<<(nl + 63) / 64, 256, 0, stream>>>(
            aggb, cur, Wnb + (size_t)l * C * C, Wrb + (size_t)l * C * C,
            bconv + (size_t)l * C, gamma + (size_t)l * C, beta + (size_t)l * C, nxt, nl,
            last ? Whb : (const unsigned short*)nullptr, bh, (float*)d_out);
        cur = nxt;
    }
}